// Round 1
// baseline (88.409 us; speedup 1.0000x reference)
//
#include <hip/hip_runtime.h>
#include <math.h>

#define N_PTS   2048
#define BLOCK   256
#define NQ      8      // queries per thread -> 2048 queries per block (whole cloud)
#define SLAB    128    // candidates staged per block
#define NSLAB   (N_PTS / SLAB)   // 16

// Grid: (32 bs, 2 dir, 16 slab) = 1024 blocks, 256 threads.
// Each block: stage 128 candidates as (x,y,z,|q|^2) in LDS, each thread tracks
// running min of (|q|^2 - 2 p.q) for its 8 query points, candidates processed
// in pairs so the two mins fuse into one v_min3_f32 (7 instrs / 2 pairs).
// Partial per-slab mins are STORED (coalesced) to ws — no atomics, no init
// memset needed; finalize min-reduces the 16 slab partials per query.
__global__ __launch_bounds__(BLOCK) void chamfer_min_kernel(
    const float* __restrict__ pred,
    const float* __restrict__ tgt,
    float* __restrict__ part)          // [64 dirbs][16 slab][2048 q]
{
    __shared__ float4 sh[SLAB];

    const int bs   = blockIdx.x;   // 0..31
    const int dir  = blockIdx.y;   // 0..1
    const int slab = blockIdx.z;   // 0..15
    const int tid  = threadIdx.x;

    const float* Abase = (dir ? tgt : pred) + (size_t)bs * N_PTS * 3;  // queries
    const float* Bbase = (dir ? pred : tgt) + (size_t)bs * N_PTS * 3;  // candidates

    // Stage this slab of candidates with |q|^2 precomputed.
    if (tid < SLAB) {
        const int j = slab * SLAB + tid;
        const float x = Bbase[3 * j + 0];
        const float y = Bbase[3 * j + 1];
        const float z = Bbase[3 * j + 2];
        sh[tid] = make_float4(x, y, z, x * x + y * y + z * z);
    }
    __syncthreads();

    // Load 8 query points; pre-scale by -2 so the pair op is pure FMA.
    float nx[NQ], ny[NQ], nz[NQ], p2[NQ], best[NQ];
    #pragma unroll
    for (int k = 0; k < NQ; ++k) {
        const int q = tid + BLOCK * k;
        const float px = Abase[3 * q + 0];
        const float py = Abase[3 * q + 1];
        const float pz = Abase[3 * q + 2];
        nx[k] = -2.0f * px;
        ny[k] = -2.0f * py;
        nz[k] = -2.0f * pz;
        p2[k] = px * px + py * py + pz * pz;
        best[k] = 3.4e38f;
    }

    // Hot loop: 2 candidates per step; fminf(fminf(best,v0),v1) -> v_min3_f32.
    #pragma unroll 4
    for (int j = 0; j < SLAB; j += 2) {
        const float4 t0 = sh[j];
        const float4 t1 = sh[j + 1];
        #pragma unroll
        for (int k = 0; k < NQ; ++k) {
            const float v0 = fmaf(nx[k], t0.x,
                             fmaf(ny[k], t0.y,
                             fmaf(nz[k], t0.z, t0.w)));   // |q|^2 - 2 p.q
            const float v1 = fmaf(nx[k], t1.x,
                             fmaf(ny[k], t1.y,
                             fmaf(nz[k], t1.z, t1.w)));
            best[k] = fminf(fminf(best[k], v0), v1);
        }
    }

    // Coalesced per-slab partial store (no clamp yet; p2+best may be ~-1e-7).
    float* dst = part + ((size_t)((dir * 32 + bs) * NSLAB + slab)) * N_PTS;
    #pragma unroll
    for (int k = 0; k < NQ; ++k)
        dst[tid + BLOCK * k] = p2[k] + best[k];
}

// 131072 queries: min over 16 slab partials -> clamp -> sqrt -> sum / 65536.
// Grid: 512 blocks x 256 threads, one query per thread; every load coalesced.
__global__ __launch_bounds__(BLOCK) void chamfer_finalize_kernel(
    const float* __restrict__ part,
    float* __restrict__ out)
{
    __shared__ float red[BLOCK / 64];
    const int g     = blockIdx.x * BLOCK + threadIdx.x;  // 0..131071
    const int dirbs = g >> 11;          // 0..63
    const int q     = g & (N_PTS - 1);  // 0..2047
    const float* src = part + ((size_t)dirbs * NSLAB) * N_PTS + q;

    float m = src[0];
    #pragma unroll
    for (int s = 1; s < NSLAB; ++s)
        m = fminf(m, src[(size_t)s * N_PTS]);

    float d = sqrtf(fmaxf(m, 0.0f));

    for (int off = 32; off > 0; off >>= 1)
        d += __shfl_down(d, off, 64);
    const int tid = threadIdx.x;
    if ((tid & 63) == 0) red[tid >> 6] = d;
    __syncthreads();
    if (tid == 0) {
        const float blk = red[0] + red[1] + red[2] + red[3];
        atomicAdd(out, blk * (1.0f / 65536.0f));  // 1/(B*S*N), N==M
    }
}

extern "C" void kernel_launch(void* const* d_in, const int* in_sizes, int n_in,
                              void* d_out, int out_size, void* d_ws, size_t ws_size,
                              hipStream_t stream) {
    const float* pred = (const float*)d_in[0];
    const float* tgt  = (const float*)d_in[1];
    float* out = (float*)d_out;
    float* part = (float*)d_ws;   // 64*16*2048 floats = 8 MB partial-min buffer

    hipMemsetAsync(out, 0, sizeof(float), stream);

    dim3 grid(32, 2, NSLAB);
    chamfer_min_kernel<<<grid, BLOCK, 0, stream>>>(pred, tgt, part);

    chamfer_finalize_kernel<<<(64 * N_PTS) / BLOCK, BLOCK, 0, stream>>>(part, out);
}

// Round 3
// 81.901 us; speedup vs baseline: 1.0795x; 1.0795x over previous
//
#include <hip/hip_runtime.h>
#include <math.h>

#define N_PTS   2048
#define BLOCK   256
#define NQ      8      // queries per thread -> 2048 queries per block (whole cloud)
#define SLAB    256    // candidates staged per block (halves atomics vs 128)
#define NSLAB   (N_PTS / SLAB)   // 8

// Grid: (32 bs, 2 dir, 8 slab) = 512 blocks, 256 threads (2 blocks/CU, 8 waves/CU).
// Round-0-proven structure: stage SLAB candidates as (x,y,z,|q|^2) in LDS, each
// thread tracks running min of (|q|^2 - 2 p.q) for its 8 query points, candidates
// processed in pairs so fminf(fminf(best,v0),v1) fuses to v_min3_f32
// (7 instr / 2 pairs instead of 8). Then clamp d^2 >= 0 and atomicMin the uint
// bit pattern into ws (uint ordering == float ordering for non-negative floats).
// 1.05M atomics total (8 per accumulator), vs 2.1M at SLAB=128.
__global__ __launch_bounds__(BLOCK) void chamfer_min_kernel(
    const float* __restrict__ pred,
    const float* __restrict__ tgt,
    unsigned int* __restrict__ wsmin)
{
    __shared__ float4 sh[SLAB];

    const int bs   = blockIdx.x;   // 0..31
    const int dir  = blockIdx.y;   // 0..1
    const int slab = blockIdx.z;   // 0..7
    const int tid  = threadIdx.x;

    const float* Abase = (dir ? tgt : pred) + (size_t)bs * N_PTS * 3;  // queries
    const float* Bbase = (dir ? pred : tgt) + (size_t)bs * N_PTS * 3;  // candidates

    // Stage this slab of candidates with |q|^2 precomputed (1 per thread).
    {
        const int j = slab * SLAB + tid;
        const float x = Bbase[3 * j + 0];
        const float y = Bbase[3 * j + 1];
        const float z = Bbase[3 * j + 2];
        sh[tid] = make_float4(x, y, z, x * x + y * y + z * z);
    }
    __syncthreads();

    // Load 8 query points; pre-scale by -2 so the pair op is pure FMA.
    float nx[NQ], ny[NQ], nz[NQ], p2[NQ], best[NQ];
    #pragma unroll
    for (int k = 0; k < NQ; ++k) {
        const int q = tid + BLOCK * k;
        const float px = Abase[3 * q + 0];
        const float py = Abase[3 * q + 1];
        const float pz = Abase[3 * q + 2];
        nx[k] = -2.0f * px;
        ny[k] = -2.0f * py;
        nz[k] = -2.0f * pz;
        p2[k] = px * px + py * py + pz * pz;
        best[k] = 3.4e38f;
    }

    // Hot loop: 2 candidates/step; fminf(fminf(best,v0),v1) -> v_min3_f32.
    #pragma unroll 2
    for (int j = 0; j < SLAB; j += 2) {
        const float4 t0 = sh[j];
        const float4 t1 = sh[j + 1];
        #pragma unroll
        for (int k = 0; k < NQ; ++k) {
            const float v0 = fmaf(nx[k], t0.x,
                             fmaf(ny[k], t0.y,
                             fmaf(nz[k], t0.z, t0.w)));   // |q|^2 - 2 p.q
            const float v1 = fmaf(nx[k], t1.x,
                             fmaf(ny[k], t1.y,
                             fmaf(nz[k], t1.z, t1.w)));
            best[k] = fminf(fminf(best[k], v0), v1);
        }
    }

    // Combine partial mins across slabs via uint atomicMin (d2 clamped >= 0).
    const int base = (dir * 32 + bs) * N_PTS;
    #pragma unroll
    for (int k = 0; k < NQ; ++k) {
        const float d2 = fmaxf(p2[k] + best[k], 0.0f);
        atomicMin(&wsmin[base + tid + BLOCK * k], __float_as_uint(d2));
    }
}

// 131072 min-d^2 values -> sqrt -> sum / 65536 -> out scalar.
// Grid: 128 blocks x 256 threads, exactly one float4 per thread.
__global__ __launch_bounds__(BLOCK) void chamfer_finalize_kernel(
    const float4* __restrict__ wsmin,
    float* __restrict__ out)
{
    __shared__ float red[BLOCK / 64];
    const int i = blockIdx.x * BLOCK + threadIdx.x;
    const float4 t = wsmin[i];
    float s = sqrtf(t.x) + sqrtf(t.y) + sqrtf(t.z) + sqrtf(t.w);

    for (int off = 32; off > 0; off >>= 1)
        s += __shfl_down(s, off, 64);
    const int tid = threadIdx.x;
    if ((tid & 63) == 0) red[tid >> 6] = s;
    __syncthreads();
    if (tid == 0) {
        const float blk = red[0] + red[1] + red[2] + red[3];
        atomicAdd(out, blk * (1.0f / 65536.0f));  // 1/(B*S*N), N==M
    }
}

extern "C" void kernel_launch(void* const* d_in, const int* in_sizes, int n_in,
                              void* d_out, int out_size, void* d_ws, size_t ws_size,
                              hipStream_t stream) {
    const float* pred = (const float*)d_in[0];
    const float* tgt  = (const float*)d_in[1];
    float* out = (float*)d_out;
    unsigned int* wsmin = (unsigned int*)d_ws;   // 2*32*2048 = 131072 uints (512 KB)

    // Init: ws to +large (0x7F7F7F7F = 3.39e38f, uint-order-consistent), out to 0.
    hipMemsetAsync(wsmin, 0x7F, (size_t)131072 * sizeof(unsigned int), stream);
    hipMemsetAsync(out, 0, sizeof(float), stream);

    dim3 grid(32, 2, NSLAB);
    chamfer_min_kernel<<<grid, BLOCK, 0, stream>>>(pred, tgt, wsmin);

    chamfer_finalize_kernel<<<131072 / (BLOCK * 4), BLOCK, 0, stream>>>(
        (const float4*)wsmin, out);
}